// Round 4
// baseline (81.873 us; speedup 1.0000x reference)
//
#include <hip/hip_runtime.h>
#include <math.h>

// WKV2D: B=8,H=16,W=16,C=256 fixed by setup_inputs().
// out[b,y,x,c] = exp( sum_{ry,rx} relu(k[b,ry,rx,c] - (|ry-y|+|rx-x|)*w[c])
//                     + relu(k[b,y,x,c]+u[c]) - relu(k[b,y,x,c]) ) * v[b,y,x,c]
// Zero-pad taps vanish (w>0.3) -> all-pairs sum over the 16x16 map + center-u
// correction. Exactness of that collapse verified R1-R3 (absmax 0.0).
//
// R4: VALU reduction via max(t0-wy,0) = max(t0,wy) - wy, correction folded per
// source row (sum_rx wy = 16*w*|ry-y_i|, closed form). 4 y-outputs/thread so
// the per-tap t0 = k - wx sub amortizes over 4 accumulators:
//   9 VALU per tap per 4 outputs (vs R3's 14). Floor ~4.3 us.
// Grid: 512 blocks = (b, 16-channel group, y-quad); 256 thr = (cl, x).
// Coalesced global (lane = channel, R3's win). LDS channel-major +4 pad.

constexpr int Bq = 8, Hq = 16, Wq = 16, Cq = 256;
constexpr int HW = Hq * Wq;     // 256
constexpr int CG = 16;          // channels per block
constexpr int YT = 4;           // y rows per thread
constexpr int ROWP = HW + 4;    // padded per-channel row (260 floats)

__global__ __launch_bounds__(256, 2)
void wkv2d_kernel(const float* __restrict__ w,
                  const float* __restrict__ u,
                  const float* __restrict__ k,
                  const float* __restrict__ v,
                  float* __restrict__ out) {
    __shared__ float klds[CG][ROWP];   // channel-major, pos contiguous

    const int bid = blockIdx.x;            // 0..511
    const int y0  = (bid & 3) * YT;        // 4 y-quads
    const int c0  = ((bid >> 2) & 15) * CG;
    const int b   = bid >> 6;

    const int tid = threadIdx.x;
    const int cl  = tid & 15;              // local channel
    const int x   = tid >> 4;              // 0..15

    // stage k[b,:,:,c0:c0+16] -> LDS channel-major (global: coalesced float4)
    #pragma unroll
    for (int i = 0; i < 4; ++i) {
        const int f = tid + 256 * i;       // float4 index 0..1023
        const int p = f >> 2;              // pos
        const int q = f & 3;               // channel quad
        const float4 kv = ((const float4*)(k + ((size_t)(b * HW + p)) * Cq + c0))[q];
        klds[4 * q + 0][p] = kv.x;
        klds[4 * q + 1][p] = kv.y;
        klds[4 * q + 2][p] = kv.z;
        klds[4 * q + 3][p] = kv.w;
    }
    __syncthreads();

    const int   c  = c0 + cl;
    const float wc = w[c];
    const float fx = (float)x;

    float wxv[16];
    #pragma unroll
    for (int rx = 0; rx < 16; ++rx)
        wxv[rx] = fabsf((float)rx - fx) * wc;

    float acc[4] = {0.f, 0.f, 0.f, 0.f};
    const float* krow = &klds[cl][0];

    #pragma unroll 4
    for (int ry = 0; ry < 16; ++ry) {
        const float fy = (float)ry;
        float wy[4], rs[4];
        #pragma unroll
        for (int i = 0; i < 4; ++i) {
            wy[i] = fabsf(fy - (float)(y0 + i)) * wc;
            rs[i] = 0.f;
        }

        const float4* rr = (const float4*)(krow + ry * 16);
        #pragma unroll
        for (int j = 0; j < 4; ++j) {
            const float4 r = rr[j];
            const float rv[4] = {r.x, r.y, r.z, r.w};
            #pragma unroll
            for (int t = 0; t < 4; ++t) {
                const float t0 = rv[t] - wxv[4 * j + t];   // shared across 4 outputs
                #pragma unroll
                for (int i = 0; i < 4; ++i)
                    rs[i] += fmaxf(t0, wy[i]);             // relu via max-identity
            }
        }
        // per-row correction: sum_rx wy = 16*wy  (keeps acc magnitude small)
        #pragma unroll
        for (int i = 0; i < 4; ++i)
            acc[i] += rs[i] - 16.0f * wy[i];
    }

    // center bonus: loop added relu(k_self); reference has relu(k_self + u)
    const float uc = u[c];
    #pragma unroll
    for (int i = 0; i < 4; ++i) {
        const float ks = krow[(y0 + i) * 16 + x];
        const float a  = acc[i] + fmaxf(ks + uc, 0.f) - fmaxf(ks, 0.f);
        const size_t idx = ((size_t)((b * 16 + y0 + i) * 16 + x)) * Cq + c;
        out[idx] = __expf(a) * v[idx];     // coalesced: lanes span 16 channels
    }
}

extern "C" void kernel_launch(void* const* d_in, const int* in_sizes, int n_in,
                              void* d_out, int out_size, void* d_ws, size_t ws_size,
                              hipStream_t stream) {
    // inputs: [0..3]=B,H,W,C (ints, fixed) [4]=w [5]=u [6]=k [7]=v, all fp32
    const float* w = (const float*)d_in[4];
    const float* u = (const float*)d_in[5];
    const float* k = (const float*)d_in[6];
    const float* v = (const float*)d_in[7];
    float* out = (float*)d_out;

    const int grid = Bq * (Cq / CG) * (Hq / YT);  // 512 blocks
    wkv2d_kernel<<<grid, 256, 0, stream>>>(w, u, k, v, out);
}